// Round 10
// baseline (85.107 us; speedup 1.0000x reference)
//
#include <hip/hip_runtime.h>

// Fully-fused 3x Minkowski sum-pool (3x3, stride 2, pad 1) with coordinate masks.
// feat (4,1024,1024,16) f32, mask (4,1024,1024) i32 -> out = concat(c2, c3).
// R10 = R7 (pair-row sweep, 512 blocks, 1 barrier/iter) with DENSE feat loads:
// unconditional clamped-address loads (no per-lane exec gating), masking applied
// at consume time via fmac with the exact-0/1 mask. Removes 6 saveexec dances
// per iteration and the mask->feat-address dependency; feat reads are streams.

constexpr int Hh = 1024, Ww = 1024;
constexpr int TW3 = 16, TH3 = 8;           // c3 tile per block
constexpr int NU = 4 * TW3 + 3;            // 67 c1 cols per block
constexpr int NV = 2 * TW3 + 1;            // 33 c2 cols per block
constexpr int NY = TW3;                    // 16 c3 cols
constexpr int NTH = 320;
constexpr int NS = 4 * TH3 + 3;            // 35 c1 rows per block sweep

// LDS-only barrier: wait own LDS ops, sync, leave global prefetch in flight.
#define BARRIER_LDS() asm volatile("s_waitcnt lgkmcnt(0)\ns_barrier" ::: "memory")

__device__ inline float4 add3(const float4& a, const float4& b, const float4& c) {
    return make_float4(a.x + b.x + c.x, a.y + b.y + c.y,
                       a.z + b.z + c.z, a.w + b.w + c.w);
}
// m0*a + m1*b + m2*c, m exact 0/1
__device__ inline float4 mad3(float m0, const float4& a, float m1, const float4& b,
                              float m2, const float4& c) {
    return make_float4(m0 * a.x + m1 * b.x + m2 * c.x,
                       m0 * a.y + m1 * b.y + m2 * c.y,
                       m0 * a.z + m1 * b.z + m2 * c.z,
                       m0 * a.w + m1 * b.w + m2 * c.w);
}

__global__ __launch_bounds__(NTH) void fused3(
    const float* __restrict__ featp, const int* __restrict__ maskp,
    float4* __restrict__ c2o, float4* __restrict__ c3o)
{
    const int j = blockIdx.x;              // col strip (c3 cols [16j,16j+16))
    const int k = blockIdx.y;              // row chunk (c3 rows [8k,8k+8))
    const int b = blockIdx.z;
    const int P0 = TW3 * j, Q0 = TH3 * k;
    const int F0 = 8 * P0 - 7;             // feat col of u=0,dw=0
    const int S0 = 4 * Q0 - 3;             // first c1 row of sweep

    const int tid = threadIdx.x;
    const int c4 = tid & 3;                // which float4 of 16 channels
    const int u  = tid >> 2;               // col role index
    const bool aAct = tid < NU * 4;        // 268 threads: rs1/c1 role
    const bool vAct = tid < NV * 4;        // 132 threads: rs2/c2 role
    const bool yAct = tid < NY * 4;        //  64 threads: rs3/c3 role

    __shared__ float4 c1m[2][NU][5];       // double-buffered (write pre-bar, read post-bar)
    __shared__ float4 c2mS[NV][5];         // written post-bar(even i), read post-bar(i+1)
    __shared__ unsigned char m1L[2][NU];
    __shared__ unsigned char m2L[NV];

    const float4* feat4 = reinterpret_cast<const float4*>(featp);
    const float4 z4 = make_float4(0.f, 0.f, 0.f, 0.f);

    auto ldMaskRow = [&](int t, int* mm) {
        mm[0] = mm[1] = mm[2] = 0;
        if (aAct && (unsigned)t < (unsigned)Hh) {
            const int base = (b * Hh + t) * Ww;
#pragma unroll
            for (int dw = 0; dw < 3; ++dw) {
                const int fc = F0 + 2 * u + dw;
                if ((unsigned)fc < (unsigned)Ww) mm[dw] = maskp[base + fc];
            }
        }
    };
    // dense, unconditional, clamped addresses; OOB killed by mask=0 at consume
    auto ldFeatRow = [&](int t, float4* ff) {
        if (aAct) {
            const int tc = min(max(t, 0), Hh - 1);
            const size_t base = (size_t)(b * Hh + tc) * Ww;
#pragma unroll
            for (int dw = 0; dw < 3; ++dw) {
                const int fc = min(max(F0 + 2 * u + dw, 0), Ww - 1);
                ff[dw] = feat4[(base + fc) * 4 + c4];
            }
        }
    };

    // ---- prologue: feat pair 0 + prev row in flight (no mask dependency),
    //      masks for pairs 0 (mE) and 1 (mO) in flight ----
    int mE[6], mO[6];   // mask buffers: pair p -> buffer (p & 1)
    float4 ffA[6];      // feat of pair i (raw, unmasked)
    float4 h_prev;      // masked rowsum of feat row 2s-1
    {
        int mP[3];
        ldMaskRow(2 * S0 - 1, mP);
        ldMaskRow(2 * S0,     mE);
        ldMaskRow(2 * S0 + 1, mE + 3);
        ldMaskRow(2 * S0 + 2, mO);
        ldMaskRow(2 * S0 + 3, mO + 3);
        float4 fP[3];
        ldFeatRow(2 * S0 - 1, fP);
        ldFeatRow(2 * S0,     ffA);
        ldFeatRow(2 * S0 + 1, ffA + 3);
        h_prev = mad3((float)mP[0], fP[0], (float)mP[1], fP[1], (float)mP[2], fP[2]);
    }

    float4 r2h0 = z4, r2h1 = z4;           // rs2 history (s-2, s-1)
    float4 r3h0 = z4, r3h1 = z4;           // rs3 history
    int m2save = 0, m3save = 0;

    // body(i): A consume feat pair i with masks MC (buffer i&1); B issue feat
    // pair i+1 and masks pair i+2 (-> same buffer MC, dead after A).
    auto body = [&](int i, int (&MC)[6]) {
        const int sb = i & 1;
        // A: consume feat pair i -> c1 row s = S0+i (masking via fmac)
        const float4 hc_e = mad3((float)MC[0], ffA[0], (float)MC[1], ffA[1],
                                 (float)MC[2], ffA[2]);
        const float4 hc_o = mad3((float)MC[3], ffA[3], (float)MC[4], ffA[4],
                                 (float)MC[5], ffA[5]);
        const int mp = MC[1] | MC[2] | MC[4] | MC[5];
        if (aAct) {
            float4 cv = z4;
            if (mp) cv = add3(h_prev, hc_e, hc_o);
            c1m[sb][u][c4] = cv;
            if (c4 == 0) m1L[sb][u] = (unsigned char)(mp ? 1 : 0);
        }
        h_prev = hc_o;
        // B: prefetch — feat pair i+1 (unconditional), masks pair i+2
        const int t2 = 2 * (S0 + i) + 2;
        if (i + 1 < NS) {
            ldFeatRow(t2,     ffA);
            ldFeatRow(t2 + 1, ffA + 3);
        }
        if (i + 2 < NS) {
            ldMaskRow(t2 + 2, MC);
            ldMaskRow(t2 + 3, MC + 3);
        }
        BARRIER_LDS();                     // the iteration's single barrier
        // C: r2 phase (post-barrier)
        float4 r2c = z4; int m2p = 0;
        if (vAct) {
            r2c = add3(c1m[sb][2 * u + 0][c4], c1m[sb][2 * u + 1][c4],
                       c1m[sb][2 * u + 2][c4]);
            m2p = m1L[sb][2 * u + 1] | m1L[sb][2 * u + 2];
        }
        if ((i & 1) == 0) {
            // c2 row r = 2*Q0 - 2 + i/2 completes; c2mS consumed at i+1
            if (vAct) {
                const int m2 = m2save | m2p;
                float4 c2v = z4;
                if (m2) c2v = add3(r2h0, r2h1, r2c);
                if (i >= 4 && u >= 1) {    // owned rows r>=2Q0, owned cols
                    const int r = 2 * Q0 - 2 + (i >> 1);
                    c2o[((size_t)((b * 256 + r) * 256 + (2 * P0 - 1 + u))) * 4 + c4] = c2v;
                }
                c2mS[u][c4] = c2v;
                if (c4 == 0) m2L[u] = (unsigned char)(m2 ? 1 : 0);
            }
        } else {
            m2save = m2p;
            // D: r3 phase — reads c2 row written post-barrier at i-1
            float4 r3c = z4; int m3p = 0;
            if (yAct) {
                r3c = add3(c2mS[2 * u + 0][c4], c2mS[2 * u + 1][c4],
                           c2mS[2 * u + 2][c4]);
                m3p = m2L[2 * u + 1] | m2L[2 * u + 2];
            }
            if (((i - 1) & 2) == 0) {      // c2 row even: save
                m3save = m3p;
            } else if (yAct && i >= 7) {   // c2 row odd: c3 row q completes
                const int m3 = m3save | m3p;
                float4 c3v = z4;
                if (m3) c3v = add3(r3h0, r3h1, r3c);
                const int q = Q0 + ((i - 7) >> 2);
                c3o[((size_t)((b * 128 + q) * 128 + (P0 + u))) * 4 + c4] = c3v;
            }
            r3h0 = r3h1; r3h1 = r3c;
        }
        r2h0 = r2h1; r2h1 = r2c;
    };

    // 2-unrolled: static mask-buffer roles (pair parity -> mE/mO). NS=35 odd.
    for (int ii = 0; ii < NS - 1; ii += 2) {
        body(ii + 0, mE);
        body(ii + 1, mO);
    }
    body(NS - 1, mE);                      // i = 34 (even)

    // epilogue: final r3/c3 (i_eff = NS = 35) reading c2mS written at i = 34
    BARRIER_LDS();
    if (yAct) {
        const float4 r3c = add3(c2mS[2 * u + 0][c4], c2mS[2 * u + 1][c4],
                                c2mS[2 * u + 2][c4]);
        const int m3p = m2L[2 * u + 1] | m2L[2 * u + 2];
        const int m3 = m3save | m3p;
        float4 c3v = z4;
        if (m3) c3v = add3(r3h0, r3h1, r3c);
        const int q = Q0 + ((NS - 7) >> 2);            // Q0 + 7
        c3o[((size_t)((b * 128 + q) * 128 + (P0 + u))) * 4 + c4] = c3v;
    }
}

extern "C" void kernel_launch(void* const* d_in, const int* in_sizes, int n_in,
                              void* d_out, int out_size, void* d_ws, size_t ws_size,
                              hipStream_t stream)
{
    const float* feat = (const float*)d_in[0];
    const int*   mask = (const int*)d_in[1];
    float4* c2 = (float4*)d_out;
    float4* c3 = c2 + (size_t)4 * 256 * 256 * 4;   // 4*256*256*16 floats ahead

    dim3 grid(Ww / (8 * TW3) /*8*/, Hh / (8 * TH3) /*16*/, 4);
    fused3<<<grid, NTH, 0, stream>>>(feat, mask, c2, c3);
}